// Round 3
// baseline (529.334 us; speedup 1.0000x reference)
//
#include <hip/hip_runtime.h>
#include <hip/hip_bf16.h>
#include <math.h>

// B=16, F=4096, Q=64, DIM=512, H=8, DH=64, MULT=2
typedef short bf16x8 __attribute__((ext_vector_type(8)));
typedef float f32x4 __attribute__((ext_vector_type(4)));

__device__ __forceinline__ f32x4 mfma16(bf16x8 a, bf16x8 b, f32x4 c) {
    return __builtin_amdgcn_mfma_f32_16x16x32_bf16(a, b, c, 0, 0, 0);
}

// manual fp32 -> bf16 round-to-nearest-even (all values finite here)
__device__ __forceinline__ unsigned short f2b(float f) {
    unsigned int x = __float_as_uint(f);
    unsigned int r = (x + 0x7fffu + ((x >> 16) & 1u)) >> 16;
    return (unsigned short)r;
}

#define GLOBAL_AS(p) ((__attribute__((address_space(1))) void*)(p))
#define LDS_AS(p)    ((__attribute__((address_space(3))) void*)(p))

// ---------------- LayerNorm: one wave per 512-elem row, fp32 in -> bf16 out --------
__global__ __launch_bounds__(256) void ln_rows(const float* __restrict__ in,
                                               const float* __restrict__ gw,
                                               const float* __restrict__ bw,
                                               unsigned short* __restrict__ out) {
    int row = blockIdx.x * 4 + (threadIdx.x >> 6);
    int lane = threadIdx.x & 63;
    const float* rp = in + (size_t)row * 512;
    float4 x0 = *(const float4*)(rp + lane * 4);
    float4 x1 = *(const float4*)(rp + 256 + lane * 4);
    float s  = x0.x + x0.y + x0.z + x0.w + x1.x + x1.y + x1.z + x1.w;
    float sq = x0.x*x0.x + x0.y*x0.y + x0.z*x0.z + x0.w*x0.w
             + x1.x*x1.x + x1.y*x1.y + x1.z*x1.z + x1.w*x1.w;
#pragma unroll
    for (int m = 1; m < 64; m <<= 1) {
        s  += __shfl_xor(s, m);
        sq += __shfl_xor(sq, m);
    }
    float mean = s * (1.0f / 512.0f);
    float var  = sq * (1.0f / 512.0f) - mean * mean;
    float rs   = rsqrtf(var + 1e-5f);
    float4 g0 = *(const float4*)(gw + lane * 4);
    float4 g1 = *(const float4*)(gw + 256 + lane * 4);
    float4 b0 = *(const float4*)(bw + lane * 4);
    float4 b1 = *(const float4*)(bw + 256 + lane * 4);
    ushort4 o0, o1;
    o0.x = f2b((x0.x - mean) * rs * g0.x + b0.x);
    o0.y = f2b((x0.y - mean) * rs * g0.y + b0.y);
    o0.z = f2b((x0.z - mean) * rs * g0.z + b0.z);
    o0.w = f2b((x0.w - mean) * rs * g0.w + b0.w);
    o1.x = f2b((x1.x - mean) * rs * g1.x + b1.x);
    o1.y = f2b((x1.y - mean) * rs * g1.y + b1.y);
    o1.z = f2b((x1.z - mean) * rs * g1.z + b1.z);
    o1.w = f2b((x1.w - mean) * rs * g1.w + b1.w);
    *(ushort4*)(out + (size_t)row * 512 + lane * 4) = o0;
    *(ushort4*)(out + (size_t)row * 512 + 256 + lane * 4) = o1;
}

// ---------------- weight transpose + fp32->bf16: out[C,R] = bf16(in[R,C]^T) --------
__global__ __launch_bounds__(256) void transpose_bf16(const float* __restrict__ in,
                                                      unsigned short* __restrict__ out,
                                                      int R, int C) {
    __shared__ float tile[32][33];
    int tx = threadIdx.x & 31, ty = threadIdx.x >> 5;
    int c0 = blockIdx.x * 32, r0 = blockIdx.y * 32;
#pragma unroll
    for (int i = 0; i < 32; i += 8)
        tile[ty + i][tx] = in[(size_t)(r0 + ty + i) * C + c0 + tx];
    __syncthreads();
#pragma unroll
    for (int i = 0; i < 32; i += 8)
        out[(size_t)(c0 + ty + i) * R + r0 + tx] = f2b(tile[tx][ty + i]);
}

// ---------------- GEMM: C[M,N] = A[M,K] * Bt[N,K]^T  (all bf16, fp32 accum) --------
// 128x128 tile, BK=32, 4 waves each 64x64. EPI: 0=store bf16, 1=relu+bf16, 2=store f32
// bf16 epilogue goes through LDS re-layout -> coalesced dwordx4 stores.
template <int EPI>
__global__ __launch_bounds__(256) void gemm_bt(const unsigned short* __restrict__ A,
                                               const unsigned short* __restrict__ Bt,
                                               void* __restrict__ Cv,
                                               int M, int N, int K) {
    __shared__ unsigned short smem[64 * 136];   // 17.4 KB: As(8K) | Bs(8K) main loop; C-bounce epi
    unsigned short* As = smem;
    unsigned short* Bs = smem + 4096;
    const int tid = threadIdx.x;
    const int wave = tid >> 6, lane = tid & 63;
    const int qd = lane >> 4, cc = lane & 15;
    const int m0 = blockIdx.y * 128, n0 = blockIdx.x * 128;
    const int wm = (wave >> 1) * 64, wn = (wave & 1) * 64;
    const int lrow = lane >> 2;        // 0..15 within a 16-row slab
    const int lcol = (lane & 3) * 8;   // element offset in k
    f32x4 acc[4][4] = {};

    for (int kt = 0; kt < K; kt += 32) {
#pragma unroll
        for (int r = 0; r < 2; ++r) {
            int slab = wave * 16 + r * 64;
            const unsigned short* ga = A + (size_t)(m0 + slab + lrow) * K + kt + lcol;
            __builtin_amdgcn_global_load_lds(GLOBAL_AS(ga), LDS_AS(&As[slab * 32]), 16, 0, 0);
            const unsigned short* gb = Bt + (size_t)(n0 + slab + lrow) * K + kt + lcol;
            __builtin_amdgcn_global_load_lds(GLOBAL_AS(gb), LDS_AS(&Bs[slab * 32]), 16, 0, 0);
        }
        __syncthreads();
        bf16x8 af[4], bfr[4];
#pragma unroll
        for (int i = 0; i < 4; ++i)
            af[i] = *(const bf16x8*)&As[(wm + i * 16 + cc) * 32 + qd * 8];
#pragma unroll
        for (int j = 0; j < 4; ++j)
            bfr[j] = *(const bf16x8*)&Bs[(wn + j * 16 + cc) * 32 + qd * 8];
#pragma unroll
        for (int i = 0; i < 4; ++i)
#pragma unroll
            for (int j = 0; j < 4; ++j)
                acc[i][j] = mfma16(af[i], bfr[j], acc[i][j]);
        __syncthreads();
    }
    if (EPI == 2) {
        // small final GEMM: scalar fp32 stores
#pragma unroll
        for (int i = 0; i < 4; ++i)
#pragma unroll
            for (int j = 0; j < 4; ++j) {
                int row = m0 + wm + i * 16 + qd * 4;
                int col = n0 + wn + j * 16 + cc;
#pragma unroll
                for (int r = 0; r < 4; ++r)
                    ((float*)Cv)[(size_t)(row + r) * N + col] = acc[i][j][r];
            }
    } else {
        // bf16 epilogue: bounce through LDS (64 rows x 128 cols per half), coalesced stores
#pragma unroll
        for (int half = 0; half < 2; ++half) {
            __syncthreads();
            if ((wave >> 1) == half) {
#pragma unroll
                for (int i = 0; i < 4; ++i)
#pragma unroll
                    for (int j = 0; j < 4; ++j)
#pragma unroll
                        for (int r = 0; r < 4; ++r) {
                            float v = acc[i][j][r];
                            if (EPI == 1) v = fmaxf(v, 0.0f);
                            smem[(i * 16 + qd * 4 + r) * 136 + wn + j * 16 + cc] = f2b(v);
                        }
            }
            __syncthreads();
            int row = tid >> 2;
            int cb = (tid & 3) * 32;
#pragma unroll
            for (int c = 0; c < 4; ++c) {
                int col = cb + c * 8;
                uint4 val = *(const uint4*)&smem[row * 136 + col];
                *(uint4*)((unsigned short*)Cv + (size_t)(m0 + half * 64 + row) * N + n0 + col) = val;
            }
        }
    }
}

// ---------------- fused masked attention, no-max softmax (values are tiny) --------
// grid = 512 blocks: (b, h, fq). Each block: ALL 64 q rows, F-quarter of 1024.
// 4 waves split the quarter into 256-f ranges; K/V frags shared across 4 q-tiles.
// softmax is shift-invariant and |sim|<~2, so no max subtraction: P = mask?exp(s):0.
// Row sums computed via MFMA against a ones-vector (no lane shuffles at all).
// Outputs per-block partial: unnormalized O (64x64 fp32) + l (64).
__global__ __launch_bounds__(256, 2) void attn_kernel(const unsigned short* __restrict__ Qb,
                                                      const unsigned short* __restrict__ Kb,
                                                      const unsigned short* __restrict__ VT,
                                                      const int* __restrict__ mask,
                                                      float* __restrict__ Opart,
                                                      float* __restrict__ lpart) {
    int blk = blockIdx.x;
    int b = blk >> 5;
    int h = (blk >> 2) & 7;
    int fq = blk & 3;
    int wave = threadIdx.x >> 6, lane = threadIdx.x & 63;
    int qd = lane >> 4, cc = lane & 15;

    __shared__ float O_lds[64][64];                // 16 KB
    __shared__ float l_lds[64];
    __shared__ unsigned short p_lds[4][16][72];    // per-wave P transpose buffer

    for (int i = threadIdx.x; i < 64 * 64; i += 256)
        ((float*)O_lds)[i] = 0.0f;
    if (threadIdx.x < 64) l_lds[threadIdx.x] = 0.0f;

    // Q fragments for all 4 q-tiles
    bf16x8 qf[4][2];
#pragma unroll
    for (int qt = 0; qt < 4; ++qt) {
        const unsigned short* qrow = Qb + (size_t)(b * 64 + qt * 16 + cc) * 512 + h * 64;
        qf[qt][0] = *(const bf16x8*)(qrow + qd * 8);
        qf[qt][1] = *(const bf16x8*)(qrow + 32 + qd * 8);
    }
    bf16x8 ones;
#pragma unroll
    for (int j = 0; j < 8; ++j) ones[j] = (short)0x3F80;  // bf16 1.0

    const unsigned short* Kbase = Kb + (size_t)b * 4096 * 512 + h * 64;
    const unsigned short* Vbase = VT + (size_t)(h * 64) * 65536 + (size_t)b * 4096;
    const int* mbase = mask + b * 4096;

    f32x4 O4[4][4] = {};
    f32x4 lac[4] = {};
    const float cexp = 0.1803368801f;   // 0.125 * log2(e)

    int fbase = fq * 1024 + wave * 256;
    for (int it = 0; it < 4; ++it) {
        int f0 = fbase + it * 64;
        bf16x8 kf[4][2], vf[4][2];
#pragma unroll
        for (int t = 0; t < 4; ++t) {
            const unsigned short* kr = Kbase + (size_t)(f0 + t * 16 + cc) * 512;
            kf[t][0] = *(const bf16x8*)(kr + qd * 8);
            kf[t][1] = *(const bf16x8*)(kr + 32 + qd * 8);
        }
#pragma unroll
        for (int g = 0; g < 4; ++g) {
            const unsigned short* vr = Vbase + (size_t)(g * 16 + cc) * 65536 + f0;
            vf[g][0] = *(const bf16x8*)(vr + qd * 8);
            vf[g][1] = *(const bf16x8*)(vr + 32 + qd * 8);
        }
        int mv[4];
#pragma unroll
        for (int t = 0; t < 4; ++t) mv[t] = mbase[f0 + t * 16 + cc];

#pragma unroll
        for (int qt = 0; qt < 4; ++qt) {
            f32x4 s4[4] = {};
#pragma unroll
            for (int t = 0; t < 4; ++t) {
                s4[t] = mfma16(qf[qt][0], kf[t][0], s4[t]);
                s4[t] = mfma16(qf[qt][1], kf[t][1], s4[t]);
            }
            // P = mask ? exp(sim) : 0   (C-layout -> per-wave LDS -> A-fragment)
#pragma unroll
            for (int t = 0; t < 4; ++t)
#pragma unroll
                for (int r = 0; r < 4; ++r) {
                    float p = mv[t] ? exp2f(s4[t][r] * cexp) : 0.0f;
                    p_lds[wave][qd * 4 + r][t * 16 + cc] = f2b(p);
                }
            bf16x8 pf0 = *(const bf16x8*)&p_lds[wave][cc][qd * 8];
            bf16x8 pf1 = *(const bf16x8*)&p_lds[wave][cc][32 + qd * 8];
            lac[qt] = mfma16(pf0, ones, lac[qt]);
            lac[qt] = mfma16(pf1, ones, lac[qt]);
#pragma unroll
            for (int g = 0; g < 4; ++g) {
                O4[qt][g] = mfma16(pf0, vf[g][0], O4[qt][g]);
                O4[qt][g] = mfma16(pf1, vf[g][1], O4[qt][g]);
            }
        }
    }
    __syncthreads();   // init of O_lds/l_lds visible to all; then accumulate
#pragma unroll
    for (int qt = 0; qt < 4; ++qt)
#pragma unroll
        for (int g = 0; g < 4; ++g)
#pragma unroll
            for (int r = 0; r < 4; ++r)
                atomicAdd(&O_lds[qt * 16 + qd * 4 + r][g * 16 + cc], O4[qt][g][r]);
    if (cc == 0) {
#pragma unroll
        for (int qt = 0; qt < 4; ++qt)
#pragma unroll
            for (int r = 0; r < 4; ++r)
                atomicAdd(&l_lds[qt * 16 + qd * 4 + r], lac[qt][r]);
    }
    __syncthreads();
    float* op = Opart + (size_t)blk * 4096;
    for (int i = threadIdx.x; i < 4096; i += 256)
        op[i] = ((const float*)O_lds)[i];
    if (threadIdx.x < 64)
        lpart[blk * 64 + threadIdx.x] = l_lds[threadIdx.x];
}

// ---------------- combine partials + normalize + FF-LayerNorm -> bf16 rows --------
// one wave per (b,q) row: gathers 8 heads x 4 f-quarters, O/l, then LN(gff,bff).
__global__ __launch_bounds__(256) void ln_combine(const float* __restrict__ Opart,
                                                  const float* __restrict__ lpart,
                                                  const float* __restrict__ gw,
                                                  const float* __restrict__ bw,
                                                  unsigned short* __restrict__ out) {
    int row = blockIdx.x * 4 + (threadIdx.x >> 6);   // b*64+q
    int lane = threadIdx.x & 63;
    int b = row >> 6, q = row & 63;
    int h = lane >> 3;
    int dh0 = (lane & 7) * 8;
    int pb = (b * 8 + h) * 4;
    float o[8] = {0,0,0,0,0,0,0,0};
    float l = 0.0f;
#pragma unroll
    for (int fq = 0; fq < 4; ++fq) {
        const float* op = Opart + (size_t)(pb + fq) * 4096 + q * 64 + dh0;
        float4 a0 = *(const float4*)op;
        float4 a1 = *(const float4*)(op + 4);
        o[0] += a0.x; o[1] += a0.y; o[2] += a0.z; o[3] += a0.w;
        o[4] += a1.x; o[5] += a1.y; o[6] += a1.z; o[7] += a1.w;
        l += lpart[(pb + fq) * 64 + q];
    }
    float inv = (l > 0.0f) ? 1.0f / l : 0.0f;
    float s = 0.0f, sq = 0.0f;
#pragma unroll
    for (int j = 0; j < 8; ++j) { o[j] *= inv; s += o[j]; sq += o[j] * o[j]; }
#pragma unroll
    for (int m = 1; m < 64; m <<= 1) {
        s  += __shfl_xor(s, m);
        sq += __shfl_xor(sq, m);
    }
    float mean = s * (1.0f / 512.0f);
    float var  = sq * (1.0f / 512.0f) - mean * mean;
    float rs   = rsqrtf(var + 1e-5f);
    int d0 = lane * 8;
    float4 g0 = *(const float4*)(gw + d0);
    float4 g1 = *(const float4*)(gw + d0 + 4);
    float4 b0 = *(const float4*)(bw + d0);
    float4 b1 = *(const float4*)(bw + d0 + 4);
    ushort4 w0, w1;
    w0.x = f2b((o[0] - mean) * rs * g0.x + b0.x);
    w0.y = f2b((o[1] - mean) * rs * g0.y + b0.y);
    w0.z = f2b((o[2] - mean) * rs * g0.z + b0.z);
    w0.w = f2b((o[3] - mean) * rs * g0.w + b0.w);
    w1.x = f2b((o[4] - mean) * rs * g1.x + b1.x);
    w1.y = f2b((o[5] - mean) * rs * g1.y + b1.y);
    w1.z = f2b((o[6] - mean) * rs * g1.z + b1.z);
    w1.w = f2b((o[7] - mean) * rs * g1.w + b1.w);
    *(ushort4*)(out + (size_t)row * 512 + d0) = w0;
    *(ushort4*)(out + (size_t)row * 512 + d0 + 4) = w1;
}

// ---------------- host ----------------
extern "C" void kernel_launch(void* const* d_in, const int* in_sizes, int n_in,
                              void* d_out, int out_size, void* d_ws, size_t ws_size,
                              hipStream_t stream) {
    const float* features = (const float*)d_in[0];
    const float* latents  = (const float*)d_in[1];
    const int*   mask     = (const int*)d_in[2];
    const float* gf  = (const float*)d_in[3];
    const float* bf_ = (const float*)d_in[4];
    const float* gl  = (const float*)d_in[5];
    const float* bl  = (const float*)d_in[6];
    const float* Wq  = (const float*)d_in[7];
    const float* Wk  = (const float*)d_in[8];
    const float* Wv  = (const float*)d_in[9];
    const float* gff = (const float*)d_in[10];
    const float* bff = (const float*)d_in[11];
    const float* W1  = (const float*)d_in[12];
    const float* W2  = (const float*)d_in[13];

    char* ws = (char*)d_ws;
    unsigned short* xn   = (unsigned short*)(ws);                    // 64 MB — dead after GEMMs
    unsigned short* Kbuf = (unsigned short*)(ws + 67108864ull);      // 64 MB (65536x512)
    unsigned short* VTb  = (unsigned short*)(ws + 134217728ull);     // 64 MB (512x65536)
    unsigned short* latn = (unsigned short*)(ws + 201326592ull);     // 1 MB
    unsigned short* Qbuf = (unsigned short*)(ws + 202375168ull);     // 1 MB
    unsigned short* ffin = (unsigned short*)(ws + 205520896ull);     // 1 MB
    unsigned short* hbuf = (unsigned short*)(ws + 206569472ull);     // 2 MB
    unsigned short* WqT  = (unsigned short*)(ws + 208666624ull);
    unsigned short* WkT  = (unsigned short*)(ws + 209190912ull);
    unsigned short* WvT  = (unsigned short*)(ws + 209715200ull);
    unsigned short* W1T  = (unsigned short*)(ws + 210239488ull);
    unsigned short* W2T  = (unsigned short*)(ws + 211288064ull);
    // attention partials reuse xn's region (xn is dead once the projections finish)
    float* Opart = (float*)(ws);                                     // 512*4096*4 = 8 MB
    float* lpart = (float*)(ws + 8388608ull);                        // 128 KB

    // weights -> bf16 transposed (N,K) layouts
    transpose_bf16<<<dim3(16, 16), 256, 0, stream>>>(Wq, WqT, 512, 512);
    transpose_bf16<<<dim3(16, 16), 256, 0, stream>>>(Wk, WkT, 512, 512);
    transpose_bf16<<<dim3(16, 16), 256, 0, stream>>>(Wv, WvT, 512, 512);
    transpose_bf16<<<dim3(32, 16), 256, 0, stream>>>(W1, W1T, 512, 1024);
    transpose_bf16<<<dim3(16, 32), 256, 0, stream>>>(W2, W2T, 1024, 512);

    // LayerNorms -> bf16
    ln_rows<<<16384, 256, 0, stream>>>(features, gf, bf_, xn);
    ln_rows<<<256, 256, 0, stream>>>(latents, gl, bl, latn);

    // K = xn @ Wk          : (65536,512)
    gemm_bt<0><<<dim3(4, 512), 256, 0, stream>>>(xn, WkT, Kbuf, 65536, 512, 512);
    // V^T = Wv^T @ xn^T    : (512,65536)  (A=WvT, Bt=xn)
    gemm_bt<0><<<dim3(512, 4), 256, 0, stream>>>(WvT, xn, VTb, 512, 65536, 512);
    // Qp = latn @ Wq       : (1024,512)
    gemm_bt<0><<<dim3(4, 8), 256, 0, stream>>>(latn, WqT, Qbuf, 1024, 512, 512);

    // fused masked attention (F-split partials), then combine + FF-LN in one pass
    attn_kernel<<<512, 256, 0, stream>>>(Qbuf, Kbuf, VTb, mask, Opart, lpart);
    ln_combine<<<256, 256, 0, stream>>>(Opart, lpart, gff, bff, ffin);

    // FF: W1 -> relu -> W2
    gemm_bt<1><<<dim3(8, 8), 256, 0, stream>>>(ffin, W1T, hbuf, 1024, 1024, 512);
    gemm_bt<2><<<dim3(4, 8), 256, 0, stream>>>(hbuf, W2T, (float*)d_out, 1024, 512, 1024);
}

// Round 4
// 451.905 us; speedup vs baseline: 1.1713x; 1.1713x over previous
//
#include <hip/hip_runtime.h>
#include <hip/hip_bf16.h>
#include <math.h>

// B=16, F=4096, Q=64, DIM=512, H=8, DH=64, MULT=2
typedef short bf16x8 __attribute__((ext_vector_type(8)));
typedef float f32x4 __attribute__((ext_vector_type(4)));

__device__ __forceinline__ f32x4 mfma16(bf16x8 a, bf16x8 b, f32x4 c) {
    return __builtin_amdgcn_mfma_f32_16x16x32_bf16(a, b, c, 0, 0, 0);
}

// manual fp32 -> bf16 round-to-nearest-even (all values finite here)
__device__ __forceinline__ unsigned short f2b(float f) {
    unsigned int x = __float_as_uint(f);
    unsigned int r = (x + 0x7fffu + ((x >> 16) & 1u)) >> 16;
    return (unsigned short)r;
}

#define GLOBAL_AS(p) ((__attribute__((address_space(1))) void*)(p))
#define LDS_AS(p)    ((__attribute__((address_space(3))) void*)(p))

// ---------------- LayerNorm: one wave per 512-elem row, fp32 in -> bf16 out --------
__global__ __launch_bounds__(256) void ln_rows(const float* __restrict__ in,
                                               const float* __restrict__ gw,
                                               const float* __restrict__ bw,
                                               unsigned short* __restrict__ out) {
    int row = blockIdx.x * 4 + (threadIdx.x >> 6);
    int lane = threadIdx.x & 63;
    const float* rp = in + (size_t)row * 512;
    float4 x0 = *(const float4*)(rp + lane * 4);
    float4 x1 = *(const float4*)(rp + 256 + lane * 4);
    float s  = x0.x + x0.y + x0.z + x0.w + x1.x + x1.y + x1.z + x1.w;
    float sq = x0.x*x0.x + x0.y*x0.y + x0.z*x0.z + x0.w*x0.w
             + x1.x*x1.x + x1.y*x1.y + x1.z*x1.z + x1.w*x1.w;
#pragma unroll
    for (int m = 1; m < 64; m <<= 1) {
        s  += __shfl_xor(s, m);
        sq += __shfl_xor(sq, m);
    }
    float mean = s * (1.0f / 512.0f);
    float var  = sq * (1.0f / 512.0f) - mean * mean;
    float rs   = rsqrtf(var + 1e-5f);
    float4 g0 = *(const float4*)(gw + lane * 4);
    float4 g1 = *(const float4*)(gw + 256 + lane * 4);
    float4 b0 = *(const float4*)(bw + lane * 4);
    float4 b1 = *(const float4*)(bw + 256 + lane * 4);
    ushort4 o0, o1;
    o0.x = f2b((x0.x - mean) * rs * g0.x + b0.x);
    o0.y = f2b((x0.y - mean) * rs * g0.y + b0.y);
    o0.z = f2b((x0.z - mean) * rs * g0.z + b0.z);
    o0.w = f2b((x0.w - mean) * rs * g0.w + b0.w);
    o1.x = f2b((x1.x - mean) * rs * g1.x + b1.x);
    o1.y = f2b((x1.y - mean) * rs * g1.y + b1.y);
    o1.z = f2b((x1.z - mean) * rs * g1.z + b1.z);
    o1.w = f2b((x1.w - mean) * rs * g1.w + b1.w);
    *(ushort4*)(out + (size_t)row * 512 + lane * 4) = o0;
    *(ushort4*)(out + (size_t)row * 512 + 256 + lane * 4) = o1;
}

// ---------------- weight transpose + fp32->bf16: out[C,R] = bf16(in[R,C]^T) --------
__global__ __launch_bounds__(256) void transpose_bf16(const float* __restrict__ in,
                                                      unsigned short* __restrict__ out,
                                                      int R, int C) {
    __shared__ float tile[32][33];
    int tx = threadIdx.x & 31, ty = threadIdx.x >> 5;
    int c0 = blockIdx.x * 32, r0 = blockIdx.y * 32;
#pragma unroll
    for (int i = 0; i < 32; i += 8)
        tile[ty + i][tx] = in[(size_t)(r0 + ty + i) * C + c0 + tx];
    __syncthreads();
#pragma unroll
    for (int i = 0; i < 32; i += 8)
        out[(size_t)(c0 + ty + i) * R + r0 + tx] = f2b(tile[tx][ty + i]);
}

// ---------------- GEMM: C[M,N] = A[M,K] * Bt[N,K]^T  (all bf16, fp32 accum) --------
// 128x128 tile, BK=32, 4 waves each 64x64. EPI: 0=store bf16, 1=relu+bf16, 2=store f32
// direct scalar stores (R2-proven; LDS-bounce epilogue regressed via bank conflicts)
template <int EPI>
__global__ __launch_bounds__(256) void gemm_bt(const unsigned short* __restrict__ A,
                                               const unsigned short* __restrict__ Bt,
                                               void* __restrict__ Cv,
                                               int M, int N, int K) {
    __shared__ unsigned short As[128 * 32];
    __shared__ unsigned short Bs[128 * 32];
    const int tid = threadIdx.x;
    const int wave = tid >> 6, lane = tid & 63;
    const int qd = lane >> 4, cc = lane & 15;
    const int m0 = blockIdx.y * 128, n0 = blockIdx.x * 128;
    const int wm = (wave >> 1) * 64, wn = (wave & 1) * 64;
    const int lrow = lane >> 2;        // 0..15 within a 16-row slab
    const int lcol = (lane & 3) * 8;   // element offset in k
    f32x4 acc[4][4] = {};

    for (int kt = 0; kt < K; kt += 32) {
#pragma unroll
        for (int r = 0; r < 2; ++r) {
            int slab = wave * 16 + r * 64;
            const unsigned short* ga = A + (size_t)(m0 + slab + lrow) * K + kt + lcol;
            __builtin_amdgcn_global_load_lds(GLOBAL_AS(ga), LDS_AS(&As[slab * 32]), 16, 0, 0);
            const unsigned short* gb = Bt + (size_t)(n0 + slab + lrow) * K + kt + lcol;
            __builtin_amdgcn_global_load_lds(GLOBAL_AS(gb), LDS_AS(&Bs[slab * 32]), 16, 0, 0);
        }
        __syncthreads();
        bf16x8 af[4], bfr[4];
#pragma unroll
        for (int i = 0; i < 4; ++i)
            af[i] = *(const bf16x8*)&As[(wm + i * 16 + cc) * 32 + qd * 8];
#pragma unroll
        for (int j = 0; j < 4; ++j)
            bfr[j] = *(const bf16x8*)&Bs[(wn + j * 16 + cc) * 32 + qd * 8];
#pragma unroll
        for (int i = 0; i < 4; ++i)
#pragma unroll
            for (int j = 0; j < 4; ++j)
                acc[i][j] = mfma16(af[i], bfr[j], acc[i][j]);
        __syncthreads();
    }
    // epilogue: C/D layout col=lane&15, row=quad*4+reg
#pragma unroll
    for (int i = 0; i < 4; ++i) {
#pragma unroll
        for (int j = 0; j < 4; ++j) {
            int row = m0 + wm + i * 16 + qd * 4;
            int col = n0 + wn + j * 16 + cc;
#pragma unroll
            for (int r = 0; r < 4; ++r) {
                float v = acc[i][j][r];
                if (EPI == 1) v = fmaxf(v, 0.0f);
                if (EPI == 2)
                    ((float*)Cv)[(size_t)(row + r) * N + col] = v;
                else
                    ((unsigned short*)Cv)[(size_t)(row + r) * N + col] = f2b(v);
            }
        }
    }
}

// ---------------- fused K+V projection: shares xn staging, 32 MFMA / K-iter ------
// K    = xn @ WkT^T        : (65536,512)   tile (m0.., n0..)
// V^T  = WvT @ xn^T        : (512,65536)   tile (n0.., m0..)
// xn LDS tile serves as A-frag for K-output and B-frag for V-output (layouts match).
__global__ __launch_bounds__(256, 2) void gemm_kv(const unsigned short* __restrict__ Xn,
                                                  const unsigned short* __restrict__ WkT,
                                                  const unsigned short* __restrict__ WvT,
                                                  unsigned short* __restrict__ Kout,
                                                  unsigned short* __restrict__ VTout) {
    __shared__ unsigned short Xs[128 * 32];
    __shared__ unsigned short Ks[128 * 32];
    __shared__ unsigned short Vs[128 * 32];
    const int tid = threadIdx.x;
    const int wave = tid >> 6, lane = tid & 63;
    const int qd = lane >> 4, cc = lane & 15;
    const int m0 = blockIdx.y * 128;   // xn row slab
    const int n0 = blockIdx.x * 128;   // weight slab
    const int wm = (wave >> 1) * 64, wn = (wave & 1) * 64;
    const int lrow = lane >> 2;
    const int lcol = (lane & 3) * 8;
    f32x4 accK[4][4] = {};
    f32x4 accV[4][4] = {};

    for (int kt = 0; kt < 512; kt += 32) {
#pragma unroll
        for (int r = 0; r < 2; ++r) {
            int slab = wave * 16 + r * 64;
            const unsigned short* gx = Xn + (size_t)(m0 + slab + lrow) * 512 + kt + lcol;
            __builtin_amdgcn_global_load_lds(GLOBAL_AS(gx), LDS_AS(&Xs[slab * 32]), 16, 0, 0);
            const unsigned short* gk = WkT + (size_t)(n0 + slab + lrow) * 512 + kt + lcol;
            __builtin_amdgcn_global_load_lds(GLOBAL_AS(gk), LDS_AS(&Ks[slab * 32]), 16, 0, 0);
            const unsigned short* gv = WvT + (size_t)(n0 + slab + lrow) * 512 + kt + lcol;
            __builtin_amdgcn_global_load_lds(GLOBAL_AS(gv), LDS_AS(&Vs[slab * 32]), 16, 0, 0);
        }
        __syncthreads();
        bf16x8 xf[4], kf[4], vf[4];
#pragma unroll
        for (int i = 0; i < 4; ++i)
            xf[i] = *(const bf16x8*)&Xs[(wm + i * 16 + cc) * 32 + qd * 8];
#pragma unroll
        for (int j = 0; j < 4; ++j) {
            kf[j] = *(const bf16x8*)&Ks[(wn + j * 16 + cc) * 32 + qd * 8];
            vf[j] = *(const bf16x8*)&Vs[(wn + j * 16 + cc) * 32 + qd * 8];
        }
#pragma unroll
        for (int i = 0; i < 4; ++i)
#pragma unroll
            for (int j = 0; j < 4; ++j) {
                accK[i][j] = mfma16(xf[i], kf[j], accK[i][j]);
                accV[j][i] = mfma16(vf[j], xf[i], accV[j][i]);
            }
        __syncthreads();
    }
    // K epilogue: rows = xn rows, cols = weight slab (N=512)
#pragma unroll
    for (int i = 0; i < 4; ++i)
#pragma unroll
        for (int j = 0; j < 4; ++j) {
            int row = m0 + wm + i * 16 + qd * 4;
            int col = n0 + wn + j * 16 + cc;
#pragma unroll
            for (int r = 0; r < 4; ++r)
                Kout[(size_t)(row + r) * 512 + col] = f2b(accK[i][j][r]);
        }
    // V^T epilogue: rows = weight slab (d), cols = xn rows (N=65536)
#pragma unroll
    for (int j = 0; j < 4; ++j)
#pragma unroll
        for (int i = 0; i < 4; ++i) {
            int row = n0 + wn + j * 16 + qd * 4;
            int col = m0 + wm + i * 16 + cc;
#pragma unroll
            for (int r = 0; r < 4; ++r)
                VTout[(size_t)(row + r) * 65536 + col] = f2b(accV[j][i][r]);
        }
}

// ---------------- fused masked attention, no-max softmax (values are tiny) --------
// grid = 512 blocks: (b, h, fq). Each block: ALL 64 q rows, F-quarter of 1024.
// 4 waves split the quarter into 256-f ranges; K/V frags shared across 4 q-tiles.
// softmax is shift-invariant and |sim|<~2, so no max subtraction: P = mask?exp(s):0.
// Row sums computed via MFMA against a ones-vector (no lane shuffles at all).
// Outputs per-block partial: unnormalized O (64x64 fp32) + l (64).
__global__ __launch_bounds__(256, 2) void attn_kernel(const unsigned short* __restrict__ Qb,
                                                      const unsigned short* __restrict__ Kb,
                                                      const unsigned short* __restrict__ VT,
                                                      const int* __restrict__ mask,
                                                      float* __restrict__ Opart,
                                                      float* __restrict__ lpart) {
    int blk = blockIdx.x;
    int b = blk >> 5;
    int h = (blk >> 2) & 7;
    int fq = blk & 3;
    int wave = threadIdx.x >> 6, lane = threadIdx.x & 63;
    int qd = lane >> 4, cc = lane & 15;

    __shared__ float O_lds[64][64];                // 16 KB
    __shared__ float l_lds[64];
    __shared__ unsigned short p_lds[4][16][72];    // per-wave P transpose buffer

    for (int i = threadIdx.x; i < 64 * 64; i += 256)
        ((float*)O_lds)[i] = 0.0f;
    if (threadIdx.x < 64) l_lds[threadIdx.x] = 0.0f;

    // Q fragments for all 4 q-tiles
    bf16x8 qf[4][2];
#pragma unroll
    for (int qt = 0; qt < 4; ++qt) {
        const unsigned short* qrow = Qb + (size_t)(b * 64 + qt * 16 + cc) * 512 + h * 64;
        qf[qt][0] = *(const bf16x8*)(qrow + qd * 8);
        qf[qt][1] = *(const bf16x8*)(qrow + 32 + qd * 8);
    }
    bf16x8 ones;
#pragma unroll
    for (int j = 0; j < 8; ++j) ones[j] = (short)0x3F80;  // bf16 1.0

    const unsigned short* Kbase = Kb + (size_t)b * 4096 * 512 + h * 64;
    const unsigned short* Vbase = VT + (size_t)(h * 64) * 65536 + (size_t)b * 4096;
    const int* mbase = mask + b * 4096;

    f32x4 O4[4][4] = {};
    f32x4 lac[4] = {};
    const float cexp = 0.1803368801f;   // 0.125 * log2(e)

    int fbase = fq * 1024 + wave * 256;
    for (int it = 0; it < 4; ++it) {
        int f0 = fbase + it * 64;
        bf16x8 kf[4][2], vf[4][2];
#pragma unroll
        for (int t = 0; t < 4; ++t) {
            const unsigned short* kr = Kbase + (size_t)(f0 + t * 16 + cc) * 512;
            kf[t][0] = *(const bf16x8*)(kr + qd * 8);
            kf[t][1] = *(const bf16x8*)(kr + 32 + qd * 8);
        }
#pragma unroll
        for (int g = 0; g < 4; ++g) {
            const unsigned short* vr = Vbase + (size_t)(g * 16 + cc) * 65536 + f0;
            vf[g][0] = *(const bf16x8*)(vr + qd * 8);
            vf[g][1] = *(const bf16x8*)(vr + 32 + qd * 8);
        }
        int mv[4];
#pragma unroll
        for (int t = 0; t < 4; ++t) mv[t] = mbase[f0 + t * 16 + cc];

#pragma unroll
        for (int qt = 0; qt < 4; ++qt) {
            f32x4 s4[4] = {};
#pragma unroll
            for (int t = 0; t < 4; ++t) {
                s4[t] = mfma16(qf[qt][0], kf[t][0], s4[t]);
                s4[t] = mfma16(qf[qt][1], kf[t][1], s4[t]);
            }
            // P = mask ? exp(sim) : 0   (C-layout -> per-wave LDS -> A-fragment)
#pragma unroll
            for (int t = 0; t < 4; ++t)
#pragma unroll
                for (int r = 0; r < 4; ++r) {
                    float p = mv[t] ? exp2f(s4[t][r] * cexp) : 0.0f;
                    p_lds[wave][qd * 4 + r][t * 16 + cc] = f2b(p);
                }
            bf16x8 pf0 = *(const bf16x8*)&p_lds[wave][cc][qd * 8];
            bf16x8 pf1 = *(const bf16x8*)&p_lds[wave][cc][32 + qd * 8];
            lac[qt] = mfma16(pf0, ones, lac[qt]);
            lac[qt] = mfma16(pf1, ones, lac[qt]);
#pragma unroll
            for (int g = 0; g < 4; ++g) {
                O4[qt][g] = mfma16(pf0, vf[g][0], O4[qt][g]);
                O4[qt][g] = mfma16(pf1, vf[g][1], O4[qt][g]);
            }
        }
    }
    __syncthreads();   // init of O_lds/l_lds visible to all; then accumulate
#pragma unroll
    for (int qt = 0; qt < 4; ++qt)
#pragma unroll
        for (int g = 0; g < 4; ++g)
#pragma unroll
            for (int r = 0; r < 4; ++r)
                atomicAdd(&O_lds[qt * 16 + qd * 4 + r][g * 16 + cc], O4[qt][g][r]);
    if (cc == 0) {
#pragma unroll
        for (int qt = 0; qt < 4; ++qt)
#pragma unroll
            for (int r = 0; r < 4; ++r)
                atomicAdd(&l_lds[qt * 16 + qd * 4 + r], lac[qt][r]);
    }
    __syncthreads();
    float* op = Opart + (size_t)blk * 4096;
    for (int i = threadIdx.x; i < 4096; i += 256)
        op[i] = ((const float*)O_lds)[i];
    if (threadIdx.x < 64)
        lpart[blk * 64 + threadIdx.x] = l_lds[threadIdx.x];
}

// ---------------- combine partials + normalize + FF-LayerNorm -> bf16 rows --------
// one wave per (b,q) row: gathers 8 heads x 4 f-quarters, O/l, then LN(gff,bff).
__global__ __launch_bounds__(256) void ln_combine(const float* __restrict__ Opart,
                                                  const float* __restrict__ lpart,
                                                  const float* __restrict__ gw,
                                                  const float* __restrict__ bw,
                                                  unsigned short* __restrict__ out) {
    int row = blockIdx.x * 4 + (threadIdx.x >> 6);   // b*64+q
    int lane = threadIdx.x & 63;
    int b = row >> 6, q = row & 63;
    int h = lane >> 3;
    int dh0 = (lane & 7) * 8;
    int pb = (b * 8 + h) * 4;
    float o[8] = {0,0,0,0,0,0,0,0};
    float l = 0.0f;
#pragma unroll
    for (int fq = 0; fq < 4; ++fq) {
        const float* op = Opart + (size_t)(pb + fq) * 4096 + q * 64 + dh0;
        float4 a0 = *(const float4*)op;
        float4 a1 = *(const float4*)(op + 4);
        o[0] += a0.x; o[1] += a0.y; o[2] += a0.z; o[3] += a0.w;
        o[4] += a1.x; o[5] += a1.y; o[6] += a1.z; o[7] += a1.w;
        l += lpart[(pb + fq) * 64 + q];
    }
    float inv = (l > 0.0f) ? 1.0f / l : 0.0f;
    float s = 0.0f, sq = 0.0f;
#pragma unroll
    for (int j = 0; j < 8; ++j) { o[j] *= inv; s += o[j]; sq += o[j] * o[j]; }
#pragma unroll
    for (int m = 1; m < 64; m <<= 1) {
        s  += __shfl_xor(s, m);
        sq += __shfl_xor(sq, m);
    }
    float mean = s * (1.0f / 512.0f);
    float var  = sq * (1.0f / 512.0f) - mean * mean;
    float rs   = rsqrtf(var + 1e-5f);
    int d0 = lane * 8;
    float4 g0 = *(const float4*)(gw + d0);
    float4 g1 = *(const float4*)(gw + d0 + 4);
    float4 b0 = *(const float4*)(bw + d0);
    float4 b1 = *(const float4*)(bw + d0 + 4);
    ushort4 w0, w1;
    w0.x = f2b((o[0] - mean) * rs * g0.x + b0.x);
    w0.y = f2b((o[1] - mean) * rs * g0.y + b0.y);
    w0.z = f2b((o[2] - mean) * rs * g0.z + b0.z);
    w0.w = f2b((o[3] - mean) * rs * g0.w + b0.w);
    w1.x = f2b((o[4] - mean) * rs * g1.x + b1.x);
    w1.y = f2b((o[5] - mean) * rs * g1.y + b1.y);
    w1.z = f2b((o[6] - mean) * rs * g1.z + b1.z);
    w1.w = f2b((o[7] - mean) * rs * g1.w + b1.w);
    *(ushort4*)(out + (size_t)row * 512 + d0) = w0;
    *(ushort4*)(out + (size_t)row * 512 + d0 + 4) = w1;
}

// ---------------- host ----------------
extern "C" void kernel_launch(void* const* d_in, const int* in_sizes, int n_in,
                              void* d_out, int out_size, void* d_ws, size_t ws_size,
                              hipStream_t stream) {
    const float* features = (const float*)d_in[0];
    const float* latents  = (const float*)d_in[1];
    const int*   mask     = (const int*)d_in[2];
    const float* gf  = (const float*)d_in[3];
    const float* bf_ = (const float*)d_in[4];
    const float* gl  = (const float*)d_in[5];
    const float* bl  = (const float*)d_in[6];
    const float* Wq  = (const float*)d_in[7];
    const float* Wk  = (const float*)d_in[8];
    const float* Wv  = (const float*)d_in[9];
    const float* gff = (const float*)d_in[10];
    const float* bff = (const float*)d_in[11];
    const float* W1  = (const float*)d_in[12];
    const float* W2  = (const float*)d_in[13];

    char* ws = (char*)d_ws;
    unsigned short* xn   = (unsigned short*)(ws);                    // 64 MB — dead after GEMMs
    unsigned short* Kbuf = (unsigned short*)(ws + 67108864ull);      // 64 MB (65536x512)
    unsigned short* VTb  = (unsigned short*)(ws + 134217728ull);     // 64 MB (512x65536)
    unsigned short* latn = (unsigned short*)(ws + 201326592ull);     // 1 MB
    unsigned short* Qbuf = (unsigned short*)(ws + 202375168ull);     // 1 MB
    unsigned short* ffin = (unsigned short*)(ws + 205520896ull);     // 1 MB
    unsigned short* hbuf = (unsigned short*)(ws + 206569472ull);     // 2 MB
    unsigned short* WqT  = (unsigned short*)(ws + 208666624ull);
    unsigned short* WkT  = (unsigned short*)(ws + 209190912ull);
    unsigned short* WvT  = (unsigned short*)(ws + 209715200ull);
    unsigned short* W1T  = (unsigned short*)(ws + 210239488ull);
    unsigned short* W2T  = (unsigned short*)(ws + 211288064ull);
    // attention partials reuse xn's region (xn is dead once the projections finish)
    float* Opart = (float*)(ws);                                     // 512*4096*4 = 8 MB
    float* lpart = (float*)(ws + 8388608ull);                        // 128 KB

    // weights -> bf16 transposed (N,K) layouts
    transpose_bf16<<<dim3(16, 16), 256, 0, stream>>>(Wq, WqT, 512, 512);
    transpose_bf16<<<dim3(16, 16), 256, 0, stream>>>(Wk, WkT, 512, 512);
    transpose_bf16<<<dim3(16, 16), 256, 0, stream>>>(Wv, WvT, 512, 512);
    transpose_bf16<<<dim3(32, 16), 256, 0, stream>>>(W1, W1T, 512, 1024);
    transpose_bf16<<<dim3(16, 32), 256, 0, stream>>>(W2, W2T, 1024, 512);

    // LayerNorms -> bf16
    ln_rows<<<16384, 256, 0, stream>>>(features, gf, bf_, xn);
    ln_rows<<<256, 256, 0, stream>>>(latents, gl, bl, latn);

    // fused K + V^T projection (shares xn staging)
    gemm_kv<<<dim3(4, 512), 256, 0, stream>>>(xn, WkT, WvT, Kbuf, VTb);
    // Qp = latn @ Wq       : (1024,512)
    gemm_bt<0><<<dim3(4, 8), 256, 0, stream>>>(latn, WqT, Qbuf, 1024, 512, 512);

    // fused masked attention (F-split partials), then combine + FF-LN in one pass
    attn_kernel<<<512, 256, 0, stream>>>(Qbuf, Kbuf, VTb, mask, Opart, lpart);
    ln_combine<<<256, 256, 0, stream>>>(Opart, lpart, gff, bff, ffin);

    // FF: W1 -> relu -> W2
    gemm_bt<1><<<dim3(8, 8), 256, 0, stream>>>(ffin, W1T, hbuf, 1024, 1024, 512);
    gemm_bt<2><<<dim3(4, 8), 256, 0, stream>>>(hbuf, W2T, (float*)d_out, 1024, 512, 1024);
}